// Round 2
// 424.780 us; speedup vs baseline: 1.0353x; 1.0353x over previous
//
#include <hip/hip_runtime.h>
#include <hip/hip_bf16.h>
#include <math.h>

#define T_TOK 8192
#define EMB   1024
#define HID   1536
#define NE    8
#define NBINB 64
#define BINTOK (T_TOK / NBINB)

typedef float  floatx4 __attribute__((ext_vector_type(4)));
typedef __bf16 bf16x8  __attribute__((ext_vector_type(8)));

// ---- workspace layout (bytes) ---- (identical to the 434us-verified session)
#define WS_COUNTS   0
#define WS_OFFSETS  1024
#define WS_FLAGS    2048
#define WS_BHIST    4096
#define WS_TOKMAP   8192        // T*8*4
#define WS_TOKLIST  270336      // NE*T*4
#define WS_YBUF     532480      // ybuf 16384*1024*2; xbf aliases it (dead before gemm2 writes)
#define WS_W1T      34086912    // 25165824
#define WS_W2T      59252736    // 25165824
#define WS_H        84418560    // hbuf 16512 rows * 1536 * 2
#define WS_NEEDED   135143424

__device__ __forceinline__ float eload(const void* p, size_t idx, bool f32) {
  return f32 ? ((const float*)p)[idx] : (float)(((const __bf16*)p)[idx]);
}

// async global->LDS, 16B per lane; LDS dest = wave-uniform base + lane*16
__device__ __forceinline__ void glds16(const void* g, void* l) {
  __builtin_amdgcn_global_load_lds(
      (const __attribute__((address_space(1))) unsigned int*)g,
      (__attribute__((address_space(3))) unsigned int*)l, 16, 0, 0);
}

// ---------------- dtype sniff ----------------
__global__ __launch_bounds__(256)
void sniff_kernel(const void* p0, const void* p1, const void* p2, const void* p3,
                  const void* p4, const void* p5, const void* p6, int* flags) {
  const void* ps[7] = {p0, p1, p2, p3, p4, p5, p6};
  const int nelem[7] = {T_TOK * EMB, EMB * NE, NE, NE * EMB * HID, NE * HID, NE * HID * EMB, NE * EMB};
  int t = blockIdx.x;
  const unsigned* w = (const unsigned*)ps[t];
  int nw = nelem[t] / 2;
  if (nw > 2048) nw = 2048;
  __shared__ int s_pl, s_nz;
  if (threadIdx.x == 0) { s_pl = 0; s_nz = 0; }
  __syncthreads();
  int pl = 0, nz = 0;
  for (int i = threadIdx.x; i < nw; i += 256) {
    unsigned v = w[i];
    if (v == 0) continue;
    nz++;
    unsigned e = (v >> 23) & 0xFF;
    if (e >= 100 && e <= 150) pl++;
  }
  atomicAdd(&s_pl, pl);
  atomicAdd(&s_nz, nz);
  __syncthreads();
  if (threadIdx.x == 0) flags[t] = (2 * s_pl > s_nz) ? 1 : 0;
}

// ---------------- logits + top-k + x->bf16 conversion: one wave per token ----------------
__global__ __launch_bounds__(256)
void logits_kernel(const void* __restrict__ x, const void* __restrict__ Wr,
                   const void* __restrict__ br, const int* __restrict__ kptr,
                   const int* __restrict__ flags, int* __restrict__ topk,
                   __bf16* __restrict__ xbf) {
  const bool xf32  = flags[0] != 0;
  const bool wrf32 = flags[1] != 0;
  const bool brf32 = flags[2] != 0;
  const int wave = threadIdx.x >> 6;
  const int lane = threadIdx.x & 63;
  const int t = blockIdx.x * 4 + wave;

  float xv[16];
  {
    size_t base = (size_t)t * EMB + lane * 16;
    if (xf32) {
      const float* g = (const float*)x + base;
#pragma unroll
      for (int j = 0; j < 16; ++j) xv[j] = g[j];
    } else {
      bf16x8 u = *(const bf16x8*)((const __bf16*)x + base);
      bf16x8 v = *(const bf16x8*)((const __bf16*)x + base + 8);
#pragma unroll
      for (int j = 0; j < 8; ++j) { xv[j] = (float)u[j]; xv[8 + j] = (float)v[j]; }
    }
  }
  // write bf16 copy of x (uniform fast path for gemm1)
  {
    bf16x8 o0, o1;
#pragma unroll
    for (int j = 0; j < 8; ++j) { o0[j] = (__bf16)xv[j]; o1[j] = (__bf16)xv[8 + j]; }
    __bf16* xo = xbf + (size_t)t * EMB + lane * 16;
    *(bf16x8*)xo = o0;
    *(bf16x8*)(xo + 8) = o1;
  }
  float acc[NE];
#pragma unroll
  for (int e = 0; e < NE; ++e) acc[e] = 0.f;
  if (wrf32) {
#pragma unroll
    for (int j = 0; j < 16; ++j) {
      const float* wr = (const float*)Wr + (size_t)(lane * 16 + j) * NE;
#pragma unroll
      for (int e = 0; e < NE; ++e) acc[e] += xv[j] * wr[e];
    }
  } else {
#pragma unroll
    for (int j = 0; j < 16; ++j) {
      bf16x8 wr = *(const bf16x8*)((const __bf16*)Wr + (size_t)(lane * 16 + j) * NE);
#pragma unroll
      for (int e = 0; e < NE; ++e) acc[e] += xv[j] * (float)wr[e];
    }
  }
#pragma unroll
  for (int e = 0; e < NE; ++e) {
#pragma unroll
    for (int off = 32; off > 0; off >>= 1)
      acc[e] += __shfl_xor(acc[e], off, 64);
  }
  if (lane == 0) {
    int k = kptr[0];
    if (k < 1) k = 1; if (k > NE) k = NE;
    float lg[NE];
#pragma unroll
    for (int e = 0; e < NE; ++e) lg[e] = acc[e] + eload(br, e, brf32);
    for (int s = 0; s < k; ++s) {
      int bi = 0; float bv = lg[0];
#pragma unroll
      for (int e = 1; e < NE; ++e) { if (lg[e] > bv) { bv = lg[e]; bi = e; } }
      lg[bi] = -3.0e38f;
      topk[t * 8 + s] = bi;
    }
  }
}

// ---------------- binning: histogram -> scan -> place ----------------
__global__ __launch_bounds__(128)
void bin1_kernel(const int* __restrict__ topk, const int* __restrict__ kptr,
                 int* __restrict__ bhist) {
  __shared__ int lhist[NE];
  if (threadIdx.x < NE) lhist[threadIdx.x] = 0;
  __syncthreads();
  int k = kptr[0];
  if (k < 1) k = 1; if (k > NE) k = NE;
  const int t = blockIdx.x * BINTOK + threadIdx.x;
  for (int s = 0; s < k; ++s) atomicAdd(&lhist[topk[t * 8 + s] & 7], 1);
  __syncthreads();
  if (threadIdx.x < NE) bhist[blockIdx.x * NE + threadIdx.x] = lhist[threadIdx.x];
}

__global__ __launch_bounds__(256)
void scan_kernel(int* __restrict__ bhist, int* __restrict__ counts, int* __restrict__ offsets) {
  __shared__ int sh[NBINB * NE];
  __shared__ int scnt[NE];
  __shared__ int soff[NE + 1];
  const int tid = threadIdx.x;
  for (int i = tid; i < NBINB * NE; i += 256) sh[i] = bhist[i];
  __syncthreads();
  if (tid < NE) {
    int s = 0;
    for (int b = 0; b < NBINB; ++b) s += sh[b * NE + tid];
    scnt[tid] = s;
  }
  __syncthreads();
  if (tid == 0) {
    int s = 0;
    for (int e = 0; e < NE; ++e) { soff[e] = s; s += scnt[e]; }
    soff[NE] = s;
  }
  __syncthreads();
  if (tid < NE) {
    int run = soff[tid];
    for (int b = 0; b < NBINB; ++b) {
      int v = sh[b * NE + tid];
      sh[b * NE + tid] = run;
      run += v;
    }
  }
  __syncthreads();
  for (int i = tid; i < NBINB * NE; i += 256) bhist[i] = sh[i];
  if (tid < NE) counts[tid] = scnt[tid];
  if (tid < NE + 1) offsets[tid] = soff[tid];
}

__global__ __launch_bounds__(128)
void bin2_kernel(const int* __restrict__ bhist, const int* __restrict__ offsets,
                 const int* __restrict__ kptr,
                 int* __restrict__ tok_list, int* __restrict__ tokmap) {
  __shared__ int lbase[NE];
  __shared__ int lcnt[NE];
  if (threadIdx.x < NE) {
    lbase[threadIdx.x] = bhist[blockIdx.x * NE + threadIdx.x];
    lcnt[threadIdx.x] = 0;
  }
  __syncthreads();
  int k = kptr[0];
  if (k < 1) k = 1; if (k > NE) k = NE;
  const int t = blockIdx.x * BINTOK + threadIdx.x;
  for (int s = 0; s < k; ++s) {
    int e = tokmap[t * 8 + s] & 7;
    int pos = atomicAdd(&lcnt[e], 1);
    int grow = lbase[e] + pos;                   // compact global row
    tok_list[e * T_TOK + (grow - offsets[e])] = t;
    tokmap[t * 8 + s] = (e << 16) | grow;
  }
}

// ---------------- per-expert transpose: [K][N] -> [N][K] bf16 ----------------
__global__ __launch_bounds__(256)
void transpose_kernel(const void* __restrict__ in, __bf16* __restrict__ out, int K, int N,
                      const int* __restrict__ flags, int fidx) {
  const bool f32 = flags[fidx] != 0;
  __shared__ __bf16 tile[64][65];
  size_t eoff = (size_t)blockIdx.z * (size_t)K * (size_t)N;
  int n0 = blockIdx.x * 64;
  int k0 = blockIdx.y * 64;
  int tx = threadIdx.x & 63;
  int ty = threadIdx.x >> 6;
#pragma unroll
  for (int i = 0; i < 16; ++i) {
    int r = i * 4 + ty;
    tile[r][tx] = (__bf16)eload(in, eoff + (size_t)(k0 + r) * N + (n0 + tx), f32);
  }
  __syncthreads();
#pragma unroll
  for (int i = 0; i < 16; ++i) {
    int r = i * 4 + ty;
    out[eoff + (size_t)(n0 + r) * K + (k0 + tx)] = tile[tx][r];
  }
}

// =====================================================================
// 256x256 grouped-GEMM core: BK=32, ring-of-4 LDS slots, counted vmcnt.
// 512 threads = 8 waves (2M x 4N), per-wave output 128x64 (acc[8][4]).
// LDS: A 4x[256][32] + B 4x[256][32] bf16 = 128 KiB, 16B-chunk XOR swizzle
// chunk^=(row>>1)&3 applied to pre-swizzled global src (linear LDS dest)
// and to ds_read addresses (rule #21: both sides, same involution).
// Race-freedom: per-wave s_waitcnt vmcnt(N) BEFORE s_barrier makes slot t
// resident for all waves at barrier release; DS in-order completion +
// compiler lgkmcnt-before-MFMA drains slot t-1 reads before next barrier,
// so STAGE4(t+3) (same physical slot) cannot overwrite live data.
// =====================================================================

#define STAGE4(TT) do {                                                  \
    const int _sl = (TT) & 3;                                            \
    __bf16* _dA = ldsA + _sl * 8192 + wave * 512;                        \
    __bf16* _dB = ldsB + _sl * 8192 + wave * 512;                        \
    const size_t _ko = (size_t)(TT) * 32;                                \
    glds16(pA0 + _ko, _dA);                                              \
    glds16(pA1 + _ko, _dA + 4096);                                       \
    glds16(pB0 + _ko, _dB);                                              \
    glds16(pB1 + _ko, _dB + 4096);                                       \
  } while (0)

#define KSTEP(TT, WAITS, DOSTAGE) do {                                   \
    asm volatile(WAITS ::: "memory");                                    \
    __builtin_amdgcn_s_barrier();                                        \
    const char* _aS = (const char*)(ldsA + ((TT) & 3) * 8192);           \
    const char* _bS = (const char*)(ldsB + ((TT) & 3) * 8192);           \
    bf16x8 _af[8], _bf[4];                                               \
    _Pragma("unroll")                                                    \
    for (int _i = 0; _i < 8; ++_i) _af[_i] = *(const bf16x8*)(_aS + aOff[_i]); \
    _Pragma("unroll")                                                    \
    for (int _j = 0; _j < 4; ++_j) _bf[_j] = *(const bf16x8*)(_bS + bOff[_j]); \
    if (DOSTAGE) STAGE4((TT) + 3);                                       \
    __builtin_amdgcn_s_setprio(1);                                       \
    _Pragma("unroll")                                                    \
    for (int _i = 0; _i < 8; ++_i)                                       \
      _Pragma("unroll")                                                  \
      for (int _j = 0; _j < 4; ++_j)                                     \
        acc[_i][_j] = __builtin_amdgcn_mfma_f32_16x16x32_bf16(_af[_i], _bf[_j], acc[_i][_j], 0, 0, 0); \
    __builtin_amdgcn_s_setprio(0);                                       \
  } while (0)

// ---------------- GEMM1: h = gelu(x_gather @ W1[e] + b1[e]) ----------------
__global__ __launch_bounds__(512, 2)
void gemm1_kernel(const __bf16* __restrict__ xbf, const __bf16* __restrict__ w1t,
                  const void* __restrict__ b1, const int* __restrict__ counts,
                  const int* __restrict__ offsets, const int* __restrict__ tok_list,
                  const int* __restrict__ flags, __bf16* __restrict__ hbuf) {
  const int flat = blockIdx.x;
  const int e   = flat & 7;              // expert -> XCD pin
  const int idx = flat >> 3;             // 0..191
  const int mT  = idx / 6;               // 0..31
  const int nT  = idx % 6;               // 0..5
  const int cnt = counts[e];
  if (mT * 256 >= cnt) return;
  const bool b1f32 = flags[4] != 0;

  __shared__ __align__(16) __bf16 ldsA[4 * 8192];
  __shared__ __align__(16) __bf16 ldsB[4 * 8192];

  const int tid  = threadIdx.x;
  const int wave = tid >> 6;
  const int lane = tid & 63;

  // staging geometry: per thread 2 rows of A and 2 of B, fixed all K-steps
  const int sr = wave * 16 + (lane >> 2);        // dest row, 0..127
  const int cA = lane & 3;                       // dest 16B chunk
  const int cg = cA ^ ((sr >> 1) & 3);           // swizzled source chunk (same for row sr+128)
  const int tokA0 = tok_list[e * T_TOK + mT * 256 + sr];       // pad entries = 0
  const int tokA1 = tok_list[e * T_TOK + mT * 256 + 128 + sr];
  const __bf16* pA0 = xbf + (size_t)tokA0 * EMB + cg * 8;
  const __bf16* pA1 = xbf + (size_t)tokA1 * EMB + cg * 8;
  const __bf16* pB0 = w1t + ((size_t)e * HID + nT * 256 + sr) * EMB + cg * 8;
  const __bf16* pB1 = w1t + ((size_t)e * HID + nT * 256 + 128 + sr) * EMB + cg * 8;

  // fragment-read byte offsets within a slot (swizzled)
  const int wm = (wave >> 2) * 128;
  const int wn = (wave & 3) * 64;
  const int fr = lane & 15;
  const int fc = lane >> 4;                      // 0..3 (k-chunk)
  int aOff[8], bOff[4];
#pragma unroll
  for (int i = 0; i < 8; ++i) { int R = wm + i * 16 + fr; aOff[i] = R * 64 + ((fc ^ ((R >> 1) & 3)) << 4); }
#pragma unroll
  for (int j = 0; j < 4; ++j) { int R = wn + j * 16 + fr; bOff[j] = R * 64 + ((fc ^ ((R >> 1) & 3)) << 4); }

  floatx4 acc[8][4];
#pragma unroll
  for (int i = 0; i < 8; ++i)
#pragma unroll
    for (int j = 0; j < 4; ++j) acc[i][j] = (floatx4){0.f, 0.f, 0.f, 0.f};

  STAGE4(0); STAGE4(1); STAGE4(2);
  const int nk = EMB / 32;                       // 32
#pragma unroll 2
  for (int t = 0; t < nk - 2; ++t) KSTEP(t, "s_waitcnt vmcnt(8)", (t + 3 < nk));
  KSTEP(nk - 2, "s_waitcnt vmcnt(4)", 0);
  KSTEP(nk - 1, "s_waitcnt vmcnt(0)", 0);

  const int hBase   = offsets[e] + mT * 256;
  const int colBase = nT * 256 + wn + fr;
  float bv[4];
#pragma unroll
  for (int j = 0; j < 4; ++j) bv[j] = eload(b1, (size_t)e * HID + colBase + j * 16, b1f32);
#pragma unroll
  for (int i = 0; i < 8; ++i) {
    const int rowLoc = wm + i * 16 + fc * 4;
#pragma unroll
    for (int r = 0; r < 4; ++r) {
      const int row = rowLoc + r;
      if (mT * 256 + row < cnt) {
        __bf16* hp = hbuf + (size_t)(hBase + row) * HID + colBase;
#pragma unroll
        for (int j = 0; j < 4; ++j) {
          float v = acc[i][j][r] + bv[j];
          float g = 0.5f * v * (1.0f + erff(v * 0.70710678118654752f));
          hp[j * 16] = (__bf16)g;
        }
      }
    }
  }
}

// ---------------- GEMM2: ybuf[row] = h @ W2[e] + b2[e] ----------------
__global__ __launch_bounds__(512, 2)
void gemm2_kernel(const __bf16* __restrict__ hbuf, const __bf16* __restrict__ w2t,
                  const void* __restrict__ b2, const int* __restrict__ counts,
                  const int* __restrict__ offsets, const int* __restrict__ flags,
                  __bf16* __restrict__ ybuf) {
  const int flat = blockIdx.x;
  const int e   = flat & 7;
  const int idx = flat >> 3;             // 0..127
  const int mT  = idx >> 2;              // 0..31
  const int nT  = idx & 3;               // 0..3
  const int cnt = counts[e];
  if (mT * 256 >= cnt) return;
  const bool b2f32 = flags[6] != 0;

  __shared__ __align__(16) __bf16 ldsA[4 * 8192];
  __shared__ __align__(16) __bf16 ldsB[4 * 8192];

  const int tid  = threadIdx.x;
  const int wave = tid >> 6;
  const int lane = tid & 63;

  const int sr = wave * 16 + (lane >> 2);
  const int cA = lane & 3;
  const int cg = cA ^ ((sr >> 1) & 3);
  const int rowBase = offsets[e] + mT * 256;
  const int lastRow = offsets[NE] - 1;           // clamp: tile may overhang expert's rows
  const int rA0 = min(rowBase + sr, lastRow);
  const int rA1 = min(rowBase + 128 + sr, lastRow);
  const __bf16* pA0 = hbuf + (size_t)rA0 * HID + cg * 8;
  const __bf16* pA1 = hbuf + (size_t)rA1 * HID + cg * 8;
  const __bf16* pB0 = w2t + ((size_t)e * EMB + nT * 256 + sr) * HID + cg * 8;
  const __bf16* pB1 = w2t + ((size_t)e * EMB + nT * 256 + 128 + sr) * HID + cg * 8;

  const int wm = (wave >> 2) * 128;
  const int wn = (wave & 3) * 64;
  const int fr = lane & 15;
  const int fc = lane >> 4;
  int aOff[8], bOff[4];
#pragma unroll
  for (int i = 0; i < 8; ++i) { int R = wm + i * 16 + fr; aOff[i] = R * 64 + ((fc ^ ((R >> 1) & 3)) << 4); }
#pragma unroll
  for (int j = 0; j < 4; ++j) { int R = wn + j * 16 + fr; bOff[j] = R * 64 + ((fc ^ ((R >> 1) & 3)) << 4); }

  floatx4 acc[8][4];
#pragma unroll
  for (int i = 0; i < 8; ++i)
#pragma unroll
    for (int j = 0; j < 4; ++j) acc[i][j] = (floatx4){0.f, 0.f, 0.f, 0.f};

  STAGE4(0); STAGE4(1); STAGE4(2);
  const int nk = HID / 32;                       // 48
#pragma unroll 2
  for (int t = 0; t < nk - 2; ++t) KSTEP(t, "s_waitcnt vmcnt(8)", (t + 3 < nk));
  KSTEP(nk - 2, "s_waitcnt vmcnt(4)", 0);
  KSTEP(nk - 1, "s_waitcnt vmcnt(0)", 0);

  const int colBase = nT * 256 + wn + fr;
  float bv[4];
#pragma unroll
  for (int j = 0; j < 4; ++j) bv[j] = eload(b2, (size_t)e * EMB + colBase + j * 16, b2f32);
#pragma unroll
  for (int i = 0; i < 8; ++i) {
    const int rowLoc = wm + i * 16 + fc * 4;
#pragma unroll
    for (int r = 0; r < 4; ++r) {
      const int row = rowLoc + r;
      if (mT * 256 + row < cnt) {
        __bf16* yp = ybuf + (size_t)(rowBase + row) * EMB + colBase;
#pragma unroll
        for (int j = 0; j < 4; ++j)
          yp[j * 16] = (__bf16)(acc[i][j][r] + bv[j]);
      }
    }
  }
}

// ---------------- combine: out[t] = (sum_s ybuf[row(t,s)]) / k ----------------
__global__ __launch_bounds__(256)
void combine_kernel(const __bf16* __restrict__ ybuf, const int* __restrict__ tokmap,
                    const int* __restrict__ kptr, const int* __restrict__ flags,
                    void* __restrict__ out) {
  const bool f32 = flags[0] != 0;
  const int wave = threadIdx.x >> 6;
  const int lane = threadIdx.x & 63;
  const int t = blockIdx.x * 4 + wave;
  int k = kptr[0];
  if (k < 1) k = 1; if (k > NE) k = NE;
  const float invk = 1.0f / (float)k;
  int rows[NE];
  for (int s = 0; s < k; ++s) rows[s] = tokmap[t * 8 + s] & 0xFFFF;
#pragma unroll
  for (int c = 0; c < 2; ++c) {
    const int i = c * 512 + lane * 8;
    float a[8];
#pragma unroll
    for (int j = 0; j < 8; ++j) a[j] = 0.f;
    for (int s = 0; s < k; ++s) {
      bf16x8 y = *(const bf16x8*)(ybuf + (size_t)rows[s] * EMB + i);
#pragma unroll
      for (int j = 0; j < 8; ++j) a[j] += (float)y[j];
    }
    if (f32) {
      float* op = (float*)out + (size_t)t * EMB + i;
      float4 u = {a[0] * invk, a[1] * invk, a[2] * invk, a[3] * invk};
      float4 v = {a[4] * invk, a[5] * invk, a[6] * invk, a[7] * invk};
      *(float4*)op = u;
      *(float4*)(op + 4) = v;
    } else {
      bf16x8 o;
#pragma unroll
      for (int j = 0; j < 8; ++j) o[j] = (__bf16)(a[j] * invk);
      *(bf16x8*)((__bf16*)out + (size_t)t * EMB + i) = o;
    }
  }
}

extern "C" void kernel_launch(void* const* d_in, const int* in_sizes, int n_in,
                              void* d_out, int out_size, void* d_ws, size_t ws_size,
                              hipStream_t stream) {
  (void)in_sizes; (void)n_in; (void)out_size;
  if (ws_size < (size_t)WS_NEEDED) return;

  const void* x  = d_in[0];
  const void* Wr = d_in[1];
  const void* br = d_in[2];
  const void* W1 = d_in[3];
  const void* b1 = d_in[4];
  const void* W2 = d_in[5];
  const void* b2 = d_in[6];
  const int* kptr = (const int*)d_in[7];

  char* ws = (char*)d_ws;
  int*    counts   = (int*)(ws + WS_COUNTS);
  int*    offsets  = (int*)(ws + WS_OFFSETS);
  int*    flags    = (int*)(ws + WS_FLAGS);
  int*    bhist    = (int*)(ws + WS_BHIST);
  int*    tokmap   = (int*)(ws + WS_TOKMAP);
  int*    tok_list = (int*)(ws + WS_TOKLIST);
  __bf16* ybuf     = (__bf16*)(ws + WS_YBUF);
  __bf16* xbf      = (__bf16*)(ws + WS_YBUF);   // aliases ybuf; dead before gemm2 writes
  __bf16* w1t      = (__bf16*)(ws + WS_W1T);
  __bf16* w2t      = (__bf16*)(ws + WS_W2T);
  __bf16* hbuf     = (__bf16*)(ws + WS_H);

  hipMemsetAsync(ws, 0, WS_YBUF, stream);

  sniff_kernel<<<dim3(7), 256, 0, stream>>>(x, Wr, br, W1, b1, W2, b2, flags);

  transpose_kernel<<<dim3(HID / 64, EMB / 64, NE), 256, 0, stream>>>(W1, w1t, EMB, HID, flags, 3);
  transpose_kernel<<<dim3(EMB / 64, HID / 64, NE), 256, 0, stream>>>(W2, w2t, HID, EMB, flags, 5);

  logits_kernel<<<dim3(T_TOK / 4), 256, 0, stream>>>(x, Wr, br, kptr, flags, tokmap, xbf);
  bin1_kernel<<<dim3(NBINB), 128, 0, stream>>>(tokmap, kptr, bhist);
  scan_kernel<<<dim3(1), 256, 0, stream>>>(bhist, counts, offsets);
  bin2_kernel<<<dim3(NBINB), 128, 0, stream>>>(bhist, offsets, kptr, tok_list, tokmap);

  gemm1_kernel<<<dim3(8 * 32 * 6), 512, 0, stream>>>(
      xbf, w1t, b1, counts, offsets, tok_list, flags, hbuf);
  gemm2_kernel<<<dim3(8 * 32 * 4), 512, 0, stream>>>(
      hbuf, w2t, b2, counts, offsets, flags, ybuf);

  combine_kernel<<<dim3(T_TOK / 4), 256, 0, stream>>>(ybuf, tokmap, kptr, flags, d_out);
}